// Round 4
// baseline (757.962 us; speedup 1.0000x reference)
//
#include <hip/hip_runtime.h>
#include <math.h>

// Equivariant graph attention (Transformer_79302276153378), MI355X fp32.
// Round 4: force w2 column residency in VGPRs via opaque asm (compiler refused
// LICM of 64 global loads in rounds 2-3: VGPR_Count=64, 1:1 load:FMA in the
// A-dot). launch_bounds(128,2) gives the allocator room (~110 VGPR -> still
// 4 waves/SIMD). Per edge: 16 ds_read_b128 + 64 FMA, zero global reloads.

constexpr int NN = 20000;
constexpr int NE = 320000;
constexpr int TE = 8;                              // edges per tile
constexpr float INV3      = 0.57735026918962576f;  // 1/sqrt(3)
constexpr float INV_SQRT8 = 0.35355339059327373f;  // 1/sqrt(R_DIM)

__device__ __forceinline__ float gelu_tanh(float p) {
    // jax.nn.gelu(approximate=True) == p * sigmoid(2*0.79788456*(p+0.044715p^3))
    float y = 0.7978845608028654f * (p + 0.044715f * p * p * p);
    return p / (1.0f + __expf(-2.0f * y));
}

// ---------------- K0: per-node dst transform ----------------
// t[n][v][8] = { s.w_ss0, s.w_ss1, (v.w_vv0)*INV3 (3), (v.w_vv1)*INV3 (3) }
__global__ __launch_bounds__(256) void node_transform_kernel(
    const float* __restrict__ node_f,
    const float* __restrict__ w_ss,   // (2,32,32)
    const float* __restrict__ w_vv,   // (2,32,32)
    float* __restrict__ t)            // (NN,32,8)
{
    __shared__ float lws[2048];
    __shared__ float lwv[2048];
    const int tid = threadIdx.x;
    for (int i = tid; i < 2048; i += 256) { lws[i] = w_ss[i]; lwv[i] = w_vv[i]; }
    __syncthreads();

    const int idx = blockIdx.x * 256 + tid;
    if (idx >= NN * 32) return;
    const int n = idx >> 5, v = idx & 31;
    const float* nf = node_f + (size_t)n * 128;

    float t0 = 0.f, t1 = 0.f;
    float tv00 = 0.f, tv01 = 0.f, tv02 = 0.f;
    float tv10 = 0.f, tv11 = 0.f, tv12 = 0.f;
    #pragma unroll
    for (int u = 0; u < 32; ++u) {
        const float s  = nf[u];
        const float vx = nf[32 + 3*u + 0];
        const float vy = nf[32 + 3*u + 1];
        const float vz = nf[32 + 3*u + 2];
        const float a = lws[u*32 + v];
        const float b = lws[1024 + u*32 + v];
        const float c = lwv[u*32 + v];
        const float d = lwv[1024 + u*32 + v];
        t0 = fmaf(s, a, t0);  t1 = fmaf(s, b, t1);
        tv00 = fmaf(vx, c, tv00); tv01 = fmaf(vy, c, tv01); tv02 = fmaf(vz, c, tv02);
        tv10 = fmaf(vx, d, tv10); tv11 = fmaf(vy, d, tv11); tv12 = fmaf(vz, d, tv12);
    }
    float4* o = (float4*)(t + (size_t)idx * 8);
    o[0] = make_float4(t0, t1, tv00 * INV3, tv01 * INV3);
    o[1] = make_float4(tv02 * INV3, tv10 * INV3, tv11 * INV3, tv12 * INV3);
}

// ---------------- CSR build ----------------
__global__ __launch_bounds__(256) void hist_kernel(
    const int* __restrict__ edst, int* __restrict__ cnt)
{
    const int e = blockIdx.x * 256 + threadIdx.x;
    if (e < NE) atomicAdd(&cnt[edst[e]], 1);
}

__global__ __launch_bounds__(256) void scan_kernel(
    const int* __restrict__ cnt, int* __restrict__ rowptr, int* __restrict__ woff)
{
    __shared__ int buf[256];
    __shared__ int carry_s;
    if (threadIdx.x == 0) carry_s = 0;
    __syncthreads();
    for (int base = 0; base < NN; base += 256) {
        const int i = base + threadIdx.x;
        const int vv = (i < NN) ? cnt[i] : 0;
        buf[threadIdx.x] = vv;
        __syncthreads();
        #pragma unroll
        for (int off = 1; off < 256; off <<= 1) {
            const int tc = (threadIdx.x >= off) ? buf[threadIdx.x - off] : 0;
            __syncthreads();
            buf[threadIdx.x] += tc;
            __syncthreads();
        }
        const int excl = buf[threadIdx.x] - vv + carry_s;   // exclusive prefix
        if (i < NN) { rowptr[i] = excl; woff[i] = excl; }
        __syncthreads();
        if (threadIdx.x == 255) carry_s += buf[255];
        __syncthreads();
    }
    if (threadIdx.x == 0) rowptr[NN] = carry_s;             // == NE
}

__global__ __launch_bounds__(256) void scatter_kernel(
    const int* __restrict__ edst, int* __restrict__ woff, int* __restrict__ perm)
{
    const int e = blockIdx.x * 256 + threadIdx.x;
    if (e < NE) {
        const int pos = atomicAdd(&woff[edst[e]], 1);
        perm[pos] = e;
    }
}

// ---------------- Phase 1: logits, block-per-node, 8-edge tiles --------------
__global__ __launch_bounds__(128, 2) void logit_kernel(
    const int*   __restrict__ rowptr,
    const int*   __restrict__ perm,
    const int*   __restrict__ esrc,
    const float* __restrict__ xattr,   // (NE,8)
    const float* __restrict__ eattr,   // (NE,4)
    const float* __restrict__ cutoff,  // (NE,)
    const float* __restrict__ node_f,  // (NN,128)
    const float* __restrict__ w1,      // (8,64)
    const float* __restrict__ w2,      // (64,128)
    const float* __restrict__ t,       // (NN,32,8)
    float* __restrict__ expw,          // (NE,) CSR order
    float* __restrict__ z)             // (NN,)
{
    __shared__ float nf[TE][128];
    __shared__ float tt[32 * 9];
    __shared__ __align__(16) float h[TE][64];
    __shared__ float xs[TE][8];
    __shared__ float eas[TE][4];
    __shared__ float cut[TE];
    __shared__ int   eid[TE];
    __shared__ int   srcid[TE];
    __shared__ float part[2][TE];

    const int n = blockIdx.x;
    const int tid = threadIdx.x;
    const int v = tid & 31, grp = tid >> 5;

    float w2c[64];
    #pragma unroll
    for (int i = 0; i < 64; ++i) w2c[i] = w2[i*128 + tid];   // coalesced per i
    #pragma unroll
    for (int i = 0; i < 64; ++i) asm volatile("" : "+v"(w2c[i]));  // pin in VGPRs
    float w1c[8];
    #pragma unroll
    for (int r = 0; r < 8; ++r) w1c[r] = w1[r*64 + (tid & 63)];
    #pragma unroll
    for (int r = 0; r < 8; ++r) asm volatile("" : "+v"(w1c[r]));

    // stage t[n] once, padded (bank-conflict-free)
    {
        const int i0 = tid, i1 = tid + 128;
        tt[(i0 >> 3) * 9 + (i0 & 7)] = t[(size_t)n * 256 + i0];
        tt[(i1 >> 3) * 9 + (i1 & 7)] = t[(size_t)n * 256 + i1];
    }

    const int k0 = rowptr[n], k1 = rowptr[n + 1];
    float zacc = 0.f;   // lanes tid<TE accumulate their edge-slot's exp

    for (int kb = k0; kb < k1; kb += TE) {
        const int nt = min(TE, k1 - kb);
        __syncthreads();                       // WAR: prev tile fully consumed
        if (tid < nt) {
            const int e = perm[kb + tid];
            eid[tid] = e; srcid[tid] = esrc[e]; cut[tid] = cutoff[e];
        }
        __syncthreads();
        for (int j = 0; j < nt; ++j)
            nf[j][tid] = node_f[(size_t)srcid[j] * 128 + tid];
        if (tid < nt * 8) xs[tid >> 3][tid & 7] = xattr[(size_t)eid[tid >> 3]*8 + (tid & 7)];
        if (tid < nt * 4) eas[tid >> 2][tid & 3] = eattr[(size_t)eid[tid >> 2]*4 + (tid & 3)];
        __syncthreads();
        #pragma unroll
        for (int r = 0; r < 4; ++r) {
            const int idx = tid + 128 * r;
            const int j = idx >> 6;
            if (j < nt) {
                float p = 0.f;
                #pragma unroll
                for (int rr = 0; rr < 8; ++rr) p = fmaf(xs[j][rr], w1c[rr], p);
                h[j][tid & 63] = gelu_tanh(p * INV_SQRT8);
            }
        }
        __syncthreads();

        for (int j = 0; j < nt; ++j) {
            const float4* h4 = (const float4*)h[j];
            float A = 0.f;
            #pragma unroll
            for (int i4 = 0; i4 < 16; ++i4) {
                const float4 hh = h4[i4];
                A = fmaf(hh.x, w2c[4*i4+0], A);
                A = fmaf(hh.y, w2c[4*i4+1], A);
                A = fmaf(hh.z, w2c[4*i4+2], A);
                A = fmaf(hh.w, w2c[4*i4+3], A);
            }
            const float a0 = eas[j][0], a10 = eas[j][1], a11 = eas[j][2], a12 = eas[j][3];
            const float s_v = nf[j][v];
            const float vx = nf[j][32 + 3*v], vy = nf[j][33 + 3*v], vz = nf[j][34 + 3*v];
            const float* tv = tt + v * 9;
            float c;
            if (grp == 0)      c = tv[0] * A * s_v * a0;
            else if (grp == 1) c = A * s_v * (tv[2]*a10 + tv[3]*a11 + tv[4]*a12);
            else if (grp == 2) c = A * a0  * (tv[5]*vx  + tv[6]*vy  + tv[7]*vz);
            else               c = tv[1] * A * (vx*a10 + vy*a11 + vz*a12) * INV3;
            #pragma unroll
            for (int m = 1; m < 64; m <<= 1) c += __shfl_xor(c, m, 64);
            if ((tid & 63) == 0) part[tid >> 6][j] = c;
        }
        __syncthreads();
        if (tid < nt) {
            const float logit = (part[0][tid] + part[1][tid]) * (0.125f / 64.0f);
            const float ex = cut[tid] * expf(logit);
            expw[kb + tid] = ex;
            zacc += ex;
        }
    }

    // reduce zacc over lanes 0..TE-1 of wave 0 and store
    if (tid < TE) {
        #pragma unroll
        for (int m = TE >> 1; m >= 1; m >>= 1) zacc += __shfl_xor(zacc, m, 64);
        if (tid == 0) z[n] = zacc;
    }
}

// ---------------- Phase 2: values, block-per-node, 8-edge tiles --------------
__global__ __launch_bounds__(128, 2) void value_kernel(
    const int*   __restrict__ rowptr,
    const int*   __restrict__ perm,
    const int*   __restrict__ esrc,
    const float* __restrict__ xattr,
    const float* __restrict__ eattr,
    const float* __restrict__ node_f,
    const float* __restrict__ w1,
    const float* __restrict__ w2,
    const float* __restrict__ expw,    // (NE,) CSR order
    const float* __restrict__ z,
    float* __restrict__ acc)           // (NN,256)
{
    __shared__ float nf[TE][128];
    __shared__ __align__(16) float h[TE][64];
    __shared__ float xs[TE][8];
    __shared__ float eas[TE][4];
    __shared__ float cf[TE];
    __shared__ int   eid[TE];
    __shared__ int   srcid[TE];

    const int n = blockIdx.x;
    const int tid = threadIdx.x;
    const int v = tid & 31, grp = tid >> 5;

    float w2c[64];
    #pragma unroll
    for (int i = 0; i < 64; ++i) w2c[i] = w2[i*128 + tid];
    #pragma unroll
    for (int i = 0; i < 64; ++i) asm volatile("" : "+v"(w2c[i]));  // pin in VGPRs
    float w1c[8];
    #pragma unroll
    for (int r = 0; r < 8; ++r) w1c[r] = w1[r*64 + (tid & 63)];
    #pragma unroll
    for (int r = 0; r < 8; ++r) asm volatile("" : "+v"(w1c[r]));

    float zv = z[n];
    if (zv == 0.f) zv = 1.f;
    const float inv_z = 1.0f / zv;
    const int k0 = rowptr[n], k1 = rowptr[n + 1];

    float ac0 = 0.f, ac1 = 0.f, ac2 = 0.f;

    for (int kb = k0; kb < k1; kb += TE) {
        const int nt = min(TE, k1 - kb);
        __syncthreads();
        if (tid < nt) {
            const int e = perm[kb + tid];
            eid[tid] = e; srcid[tid] = esrc[e];
            cf[tid] = sqrtf(expw[kb + tid] * inv_z) * 0.125f;  // sqrt(alpha)/8
        }
        __syncthreads();
        for (int j = 0; j < nt; ++j)
            nf[j][tid] = node_f[(size_t)srcid[j] * 128 + tid];
        if (tid < nt * 8) xs[tid >> 3][tid & 7] = xattr[(size_t)eid[tid >> 3]*8 + (tid & 7)];
        if (tid < nt * 4) eas[tid >> 2][tid & 3] = eattr[(size_t)eid[tid >> 2]*4 + (tid & 3)];
        __syncthreads();
        #pragma unroll
        for (int r = 0; r < 4; ++r) {
            const int idx = tid + 128 * r;
            const int j = idx >> 6;
            if (j < nt) {
                float p = 0.f;
                #pragma unroll
                for (int rr = 0; rr < 8; ++rr) p = fmaf(xs[j][rr], w1c[rr], p);
                h[j][tid & 63] = gelu_tanh(p * INV_SQRT8);
            }
        }
        __syncthreads();

        for (int j = 0; j < nt; ++j) {
            const float4* h4 = (const float4*)h[j];
            float A = 0.f;
            #pragma unroll
            for (int i4 = 0; i4 < 16; ++i4) {
                const float4 hh = h4[i4];
                A = fmaf(hh.x, w2c[4*i4+0], A);
                A = fmaf(hh.y, w2c[4*i4+1], A);
                A = fmaf(hh.z, w2c[4*i4+2], A);
                A = fmaf(hh.w, w2c[4*i4+3], A);
            }
            const float a0 = eas[j][0], a10 = eas[j][1], a11 = eas[j][2], a12 = eas[j][3];
            const float s_v = nf[j][v];
            const float vx = nf[j][32 + 3*v], vy = nf[j][33 + 3*v], vz = nf[j][34 + 3*v];
            const float cA = cf[j] * A;
            if (grp == 0) {
                ac0 = fmaf(cA, s_v * a0, ac0);
            } else if (grp == 1) {
                const float tq = cA * s_v;
                ac0 = fmaf(tq, a10, ac0); ac1 = fmaf(tq, a11, ac1); ac2 = fmaf(tq, a12, ac2);
            } else if (grp == 2) {
                const float tq = cA * a0;
                ac0 = fmaf(tq, vx, ac0);  ac1 = fmaf(tq, vy, ac1);  ac2 = fmaf(tq, vz, ac2);
            } else {
                ac0 = fmaf(cA * INV3, vx*a10 + vy*a11 + vz*a12, ac0);
            }
        }
    }

    float* ad = acc + (size_t)n * 256;
    if (grp == 0)      { ad[v] = ac0; }
    else if (grp == 3) { ad[32 + v] = ac0; }
    else if (grp == 1) { ad[64  + 3*v] = ac0; ad[65  + 3*v] = ac1; ad[66  + 3*v] = ac2; }
    else               { ad[160 + 3*v] = ac0; ad[161 + 3*v] = ac1; ad[162 + 3*v] = ac2; }
}

// ---------------- K3: final node linears ----------------
__global__ __launch_bounds__(256) void node_out_kernel(
    const float* __restrict__ acc,     // (NN,256)
    const float* __restrict__ lin_ws,  // (64,32)
    const float* __restrict__ lin_wv,  // (64,32)
    float* __restrict__ out)           // (NN,128)
{
    const int idx = blockIdx.x * 256 + threadIdx.x;
    if (idx >= NN * 32) return;
    const int n = idx >> 5, o = idx & 31;
    const float* a = acc + (size_t)n * 256;

    float os = 0.f, ov0 = 0.f, ov1 = 0.f, ov2 = 0.f;
    #pragma unroll
    for (int u = 0; u < 64; ++u) {
        os = fmaf(a[u], lin_ws[u*32 + o], os);
        const float w = lin_wv[u*32 + o];
        ov0 = fmaf(a[64 + 3*u + 0], w, ov0);
        ov1 = fmaf(a[64 + 3*u + 1], w, ov1);
        ov2 = fmaf(a[64 + 3*u + 2], w, ov2);
    }
    float* on = out + (size_t)n * 128;
    on[o]            = os  * 0.125f;
    on[32 + 3*o + 0] = ov0 * 0.125f;
    on[32 + 3*o + 1] = ov1 * 0.125f;
    on[32 + 3*o + 2] = ov2 * 0.125f;
}

extern "C" void kernel_launch(void* const* d_in, const int* in_sizes, int n_in,
                              void* d_out, int out_size, void* d_ws, size_t ws_size,
                              hipStream_t stream) {
    const int*   esrc    = (const int*)  d_in[0];
    const int*   edst    = (const int*)  d_in[1];
    const float* xattr   = (const float*)d_in[2];
    const float* eattr   = (const float*)d_in[3];
    const float* cutoff  = (const float*)d_in[4];
    const float* node_f  = (const float*)d_in[5];
    const float* k_w1    = (const float*)d_in[6];
    const float* k_w2    = (const float*)d_in[7];
    const float* v_w1    = (const float*)d_in[8];
    const float* v_w2    = (const float*)d_in[9];
    const float* w_ss    = (const float*)d_in[10];
    const float* w_vv    = (const float*)d_in[11];
    const float* lin_ws  = (const float*)d_in[12];
    const float* lin_wv  = (const float*)d_in[13];
    float* out = (float*)d_out;

    // workspace: floats [t NN*256 | acc NN*256 | z NN | expw NE] then
    //            ints   [cnt NN | rowptr NN+1 | woff NN | perm NE]
    float* t    = (float*)d_ws;
    float* acc  = t + (size_t)NN * 256;
    float* z    = acc + (size_t)NN * 256;
    float* expw = z + NN;
    int*   cnt    = (int*)(expw + NE);
    int*   rowptr = cnt + NN;
    int*   woff   = rowptr + NN + 1;
    int*   perm   = woff + NN;

    hipMemsetAsync(cnt, 0, NN * sizeof(int), stream);

    node_transform_kernel<<<(NN*32 + 255)/256, 256, 0, stream>>>(node_f, w_ss, w_vv, t);

    hist_kernel<<<(NE + 255)/256, 256, 0, stream>>>(edst, cnt);
    scan_kernel<<<1, 256, 0, stream>>>(cnt, rowptr, woff);
    scatter_kernel<<<(NE + 255)/256, 256, 0, stream>>>(edst, woff, perm);

    logit_kernel<<<NN, 128, 0, stream>>>(
        rowptr, perm, esrc, xattr, eattr, cutoff, node_f, k_w1, k_w2, t, expw, z);

    value_kernel<<<NN, 128, 0, stream>>>(
        rowptr, perm, esrc, xattr, eattr, node_f, v_w1, v_w2, expw, z, acc);

    node_out_kernel<<<(NN*32 + 255)/256, 256, 0, stream>>>(acc, lin_ws, lin_wv, out);
}

// Round 5
// 440.179 us; speedup vs baseline: 1.7219x; 1.7219x over previous
//
#include <hip/hip_runtime.h>
#include <math.h>

// Equivariant graph attention (Transformer_79302276153378), MI355X.
// Round 5: MFMA for the edge MLP second layer (A = H @ w2, 3-term bf16 split).
// edge_gemm_kernel: 64 edges/block; logit fused via P.t[dst] (coalesced);
// A_v stored bf16. value_kernel: light CSR gather epilogue, no GEMV.

constexpr int NN = 20000;
constexpr int NE = 320000;
constexpr int TE = 8;
constexpr float INV3      = 0.57735026918962576f;  // 1/sqrt(3)
constexpr float INV_SQRT8 = 0.35355339059327373f;  // 1/sqrt(R_DIM)

typedef __attribute__((ext_vector_type(8))) short bf16x8;
typedef __attribute__((ext_vector_type(4))) float f32x4;

__device__ __forceinline__ float gelu_tanh(float p) {
    float y = 0.7978845608028654f * (p + 0.044715f * p * p * p);
    return p / (1.0f + __expf(-2.0f * y));
}
__device__ __forceinline__ ushort bf16_rn(float f) {
    unsigned u = __float_as_uint(f);
    unsigned r = (u + 0x7FFFu + ((u >> 16) & 1u)) >> 16;
    return (ushort)r;
}
__device__ __forceinline__ float bf16_f(ushort h) {
    return __uint_as_float(((unsigned)h) << 16);
}

// ---------------- K0: per-node dst transform ----------------
__global__ __launch_bounds__(256) void node_transform_kernel(
    const float* __restrict__ node_f,
    const float* __restrict__ w_ss,
    const float* __restrict__ w_vv,
    float* __restrict__ t)            // (NN,32,8)
{
    __shared__ float lws[2048];
    __shared__ float lwv[2048];
    const int tid = threadIdx.x;
    for (int i = tid; i < 2048; i += 256) { lws[i] = w_ss[i]; lwv[i] = w_vv[i]; }
    __syncthreads();

    const int idx = blockIdx.x * 256 + tid;
    if (idx >= NN * 32) return;
    const int n = idx >> 5, v = idx & 31;
    const float* nf = node_f + (size_t)n * 128;

    float t0 = 0.f, t1 = 0.f;
    float tv00 = 0.f, tv01 = 0.f, tv02 = 0.f;
    float tv10 = 0.f, tv11 = 0.f, tv12 = 0.f;
    #pragma unroll
    for (int u = 0; u < 32; ++u) {
        const float s  = nf[u];
        const float vx = nf[32 + 3*u + 0];
        const float vy = nf[32 + 3*u + 1];
        const float vz = nf[32 + 3*u + 2];
        const float a = lws[u*32 + v];
        const float b = lws[1024 + u*32 + v];
        const float c = lwv[u*32 + v];
        const float d = lwv[1024 + u*32 + v];
        t0 = fmaf(s, a, t0);  t1 = fmaf(s, b, t1);
        tv00 = fmaf(vx, c, tv00); tv01 = fmaf(vy, c, tv01); tv02 = fmaf(vz, c, tv02);
        tv10 = fmaf(vx, d, tv10); tv11 = fmaf(vy, d, tv11); tv12 = fmaf(vz, d, tv12);
    }
    float4* o = (float4*)(t + (size_t)idx * 8);
    o[0] = make_float4(t0, t1, tv00 * INV3, tv01 * INV3);
    o[1] = make_float4(tv02 * INV3, tv10 * INV3, tv11 * INV3, tv12 * INV3);
}

// ---------------- CSR build ----------------
__global__ __launch_bounds__(256) void hist_kernel(
    const int* __restrict__ edst, int* __restrict__ cnt)
{
    const int e = blockIdx.x * 256 + threadIdx.x;
    if (e < NE) atomicAdd(&cnt[edst[e]], 1);
}

__global__ __launch_bounds__(256) void scan_kernel(
    const int* __restrict__ cnt, int* __restrict__ rowptr, int* __restrict__ woff)
{
    __shared__ int buf[256];
    __shared__ int carry_s;
    if (threadIdx.x == 0) carry_s = 0;
    __syncthreads();
    for (int base = 0; base < NN; base += 256) {
        const int i = base + threadIdx.x;
        const int vv = (i < NN) ? cnt[i] : 0;
        buf[threadIdx.x] = vv;
        __syncthreads();
        #pragma unroll
        for (int off = 1; off < 256; off <<= 1) {
            const int tc = (threadIdx.x >= off) ? buf[threadIdx.x - off] : 0;
            __syncthreads();
            buf[threadIdx.x] += tc;
            __syncthreads();
        }
        const int excl = buf[threadIdx.x] - vv + carry_s;
        if (i < NN) { rowptr[i] = excl; woff[i] = excl; }
        __syncthreads();
        if (threadIdx.x == 255) carry_s += buf[255];
        __syncthreads();
    }
    if (threadIdx.x == 0) rowptr[NN] = carry_s;
}

__global__ __launch_bounds__(256) void scatter_kernel(
    const int* __restrict__ edst, int* __restrict__ woff, int* __restrict__ perm)
{
    const int e = blockIdx.x * 256 + threadIdx.x;
    if (e < NE) {
        const int pos = atomicAdd(&woff[edst[e]], 1);
        perm[pos] = e;
    }
}

// ---------------- edge GEMM + fused logit (k) + A_v store (v) ----------------
// 64 edges/block, 256 threads (4 waves, each one 16-edge M-tile).
// A-frag: row=lane&15, k=(lane>>4)*8+e (H1 hypothesis). C: col=lane&15,
// row=(lane>>4)*4+reg (m89-verified). XOR swizzle ^((row&7)<<3) on k for
// conflict-free ds_read_b128.
__global__ __launch_bounds__(256, 3) void edge_gemm_kernel(
    const int*   __restrict__ esrc,
    const int*   __restrict__ edst,
    const float* __restrict__ xattr,
    const float* __restrict__ eattr,
    const float* __restrict__ cutoff,
    const float* __restrict__ node_f,
    const float* __restrict__ k_w1,
    const float* __restrict__ k_w2,
    const float* __restrict__ v_w1,
    const float* __restrict__ v_w2,
    const float* __restrict__ t,       // (NN,256)
    float* __restrict__ expw,          // (NE,) edge order
    float* __restrict__ z,             // (NN,) atomic
    ushort* __restrict__ Avb)          // (NE,128) bf16
{
    __shared__ ushort W2h[8192], W2l[8192];   // [n:128][k:64] swizzled
    __shared__ ushort Hh[4096],  Hl[4096];    // [e:64][k:64] swizzled
    __shared__ float  xs[64][8];
    __shared__ float  seat[64][4];
    __shared__ int    sdst[64], ssrc[64];

    const int tid  = threadIdx.x;
    const int e0   = blockIdx.x * 64;
    const int lane = tid & 63, wv = tid >> 6;
    const int c    = lane & 15, g = lane >> 4;
    const int j    = lane;                    // hidden index for H compute

    { // one-time staging
        int i = tid;
        xs[i >> 3][i & 7] = xattr[(size_t)e0*8 + i];
        i = tid + 256;
        xs[i >> 3][i & 7] = xattr[(size_t)e0*8 + i];
        seat[tid >> 2][tid & 3] = eattr[(size_t)e0*4 + tid];
        if (tid < 64) { sdst[tid] = edst[e0 + tid]; ssrc[tid] = esrc[e0 + tid]; }
    }

    for (int ph = 0; ph < 2; ++ph) {
        const float* w1 = ph ? v_w1 : k_w1;
        const float* w2 = ph ? v_w2 : k_w2;
        __syncthreads();   // prev phase LDS reads done (and initial stage visible)

        // stage w2^T split into LDS (swizzled)
        for (int i = tid; i < 8192; i += 256) {
            const int k = i >> 7, n = i & 127;
            const float f = w2[i];
            const ushort hi = bf16_rn(f);
            const ushort lo = bf16_rn(f - bf16_f(hi));
            const int sw = (n << 6) | (k ^ ((n & 7) << 3));
            W2h[sw] = hi; W2l[sw] = lo;
        }
        // H = gelu(x @ w1 / sqrt(8)), split, store swizzled
        float w1c[8];
        #pragma unroll
        for (int r = 0; r < 8; ++r) w1c[r] = w1[r*64 + j];
        #pragma unroll
        for (int tt = 0; tt < 16; ++tt) {
            const int e = (tid >> 6) + 4*tt;
            const float4* xp = (const float4*)xs[e];
            const float4 x0 = xp[0], x1 = xp[1];
            float p = x0.x*w1c[0];
            p = fmaf(x0.y, w1c[1], p); p = fmaf(x0.z, w1c[2], p);
            p = fmaf(x0.w, w1c[3], p); p = fmaf(x1.x, w1c[4], p);
            p = fmaf(x1.y, w1c[5], p); p = fmaf(x1.z, w1c[6], p);
            p = fmaf(x1.w, w1c[7], p);
            const float h = gelu_tanh(p * INV_SQRT8);
            const ushort hi = bf16_rn(h);
            const ushort lo = bf16_rn(h - bf16_f(hi));
            const int sw = (e << 6) | (j ^ ((e & 7) << 3));
            Hh[sw] = hi; Hl[sw] = lo;
        }
        __syncthreads();

        // MFMA: wave wv owns edges [eb, eb+16)
        const int eb = wv * 16;
        bf16x8 ah[2], al[2];
        #pragma unroll
        for (int ks = 0; ks < 2; ++ks) {
            const int row = eb + c;
            const int kb  = ks*32 + g*8;
            const int ad  = (row << 6) | (kb ^ ((row & 7) << 3));
            ah[ks] = *(const bf16x8*)&Hh[ad];
            al[ks] = *(const bf16x8*)&Hl[ad];
        }
        f32x4 acc[8];
        #pragma unroll
        for (int nt = 0; nt < 8; ++nt) acc[nt] = (f32x4){0.f, 0.f, 0.f, 0.f};
        #pragma unroll
        for (int nt = 0; nt < 8; ++nt) {
            const int n = nt*16 + c;
            #pragma unroll
            for (int ks = 0; ks < 2; ++ks) {
                const int kb = ks*32 + g*8;
                const int bd = (n << 6) | (kb ^ ((n & 7) << 3));
                const bf16x8 bh = *(const bf16x8*)&W2h[bd];
                const bf16x8 bl = *(const bf16x8*)&W2l[bd];
                acc[nt] = __builtin_amdgcn_mfma_f32_16x16x32_bf16(ah[ks], bh, acc[nt], 0, 0, 0);
                acc[nt] = __builtin_amdgcn_mfma_f32_16x16x32_bf16(al[ks], bh, acc[nt], 0, 0, 0);
                acc[nt] = __builtin_amdgcn_mfma_f32_16x16x32_bf16(ah[ks], bl, acc[nt], 0, 0, 0);
            }
        }

        if (ph == 0) {
            // fused logit: logit_e = (P_e . t[dst]) * 0.125/64
            float contrib[4] = {0.f, 0.f, 0.f, 0.f};
            #pragma unroll
            for (int r = 0; r < 4; ++r) {
                const int el  = eb + g*4 + r;
                const int dst = sdst[el], src = ssrc[el];
                const float a0  = seat[el][0], a1x = seat[el][1];
                const float a1y = seat[el][2], a1z = seat[el][3];
                const float* tp = t + (size_t)dst * 256;
                const float* np = node_f + (size_t)src * 128;
                #pragma unroll
                for (int hf = 0; hf < 2; ++hf) {
                    const int v = c + 16*hf;
                    const float A0 = acc[0+hf][r], A1 = acc[2+hf][r];
                    const float A2 = acc[4+hf][r], A3 = acc[6+hf][r];
                    const float4 t4a = *(const float4*)(tp + v*8);
                    const float4 t4b = *(const float4*)(tp + v*8 + 4);
                    const float s_v = np[v];
                    const float vx = np[32+3*v], vy = np[33+3*v], vz = np[34+3*v];
                    const float svd = vx*a1x + vy*a1y + vz*a1z;
                    contrib[r] += t4a.x * (A0 * s_v * a0)
                                + t4a.y * (A3 * svd * INV3)
                                + (A1 * s_v) * (t4a.z*a1x + t4a.w*a1y + t4b.x*a1z)
                                + (A2 * a0)  * (t4b.y*vx + t4b.z*vy + t4b.w*vz);
                }
            }
            #pragma unroll
            for (int r = 0; r < 4; ++r) {
                #pragma unroll
                for (int m = 1; m < 16; m <<= 1)
                    contrib[r] += __shfl_xor(contrib[r], m, 64);
            }
            if (c == 0) {
                #pragma unroll
                for (int r = 0; r < 4; ++r) {
                    const int el = eb + g*4 + r;
                    const int e  = e0 + el;
                    const float logit = contrib[r] * (0.125f / 64.0f);
                    const float ex = cutoff[e] * expf(logit);
                    expw[e] = ex;
                    unsafeAtomicAdd(&z[sdst[el]], ex);
                }
            }
        } else {
            // store A_v as bf16, coalesced per 16-col segment
            #pragma unroll
            for (int nt = 0; nt < 8; ++nt) {
                #pragma unroll
                for (int r = 0; r < 4; ++r) {
                    const int el = eb + g*4 + r;
                    Avb[(size_t)(e0 + el)*128 + nt*16 + c] = bf16_rn(acc[nt][r]);
                }
            }
        }
    }
}

// ---------------- values: block-per-node CSR, light epilogue ----------------
__global__ __launch_bounds__(128, 4) void value_kernel(
    const int*   __restrict__ rowptr,
    const int*   __restrict__ perm,
    const int*   __restrict__ esrc,
    const float* __restrict__ eattr,
    const float* __restrict__ node_f,
    const ushort* __restrict__ Avb,    // (NE,128) bf16
    const float* __restrict__ expw,    // (NE,) edge order
    const float* __restrict__ z,
    float* __restrict__ acc)           // (NN,256)
{
    __shared__ float nf[TE][128];
    __shared__ float eas[TE][4];
    __shared__ float cf[TE];
    __shared__ int   eid[TE];
    __shared__ int   srcid[TE];

    const int n = blockIdx.x;
    const int tid = threadIdx.x;
    const int v = tid & 31, grp = tid >> 5;

    float zv = z[n];
    if (zv == 0.f) zv = 1.f;
    const float inv_z = 1.0f / zv;
    const int k0 = rowptr[n], k1 = rowptr[n + 1];

    float ac0 = 0.f, ac1 = 0.f, ac2 = 0.f;

    for (int kb = k0; kb < k1; kb += TE) {
        const int nt = min(TE, k1 - kb);
        __syncthreads();
        if (tid < nt) {
            const int e = perm[kb + tid];
            eid[tid] = e; srcid[tid] = esrc[e];
            cf[tid] = sqrtf(expw[e] * inv_z) * 0.125f;   // sqrt(alpha)/8
        }
        __syncthreads();
        for (int jj = 0; jj < nt; ++jj)
            nf[jj][tid] = node_f[(size_t)srcid[jj] * 128 + tid];
        if (tid < nt * 4) eas[tid >> 2][tid & 3] = eattr[(size_t)eid[tid >> 2]*4 + (tid & 3)];
        __syncthreads();

        for (int jj = 0; jj < nt; ++jj) {
            const float A = bf16_f(Avb[(size_t)eid[jj]*128 + tid]);
            const float a0 = eas[jj][0], a10 = eas[jj][1], a11 = eas[jj][2], a12 = eas[jj][3];
            const float s_v = nf[jj][v];
            const float vx = nf[jj][32 + 3*v], vy = nf[jj][33 + 3*v], vz = nf[jj][34 + 3*v];
            const float cA = cf[jj] * A;
            if (grp == 0) {
                ac0 = fmaf(cA, s_v * a0, ac0);
            } else if (grp == 1) {
                const float tq = cA * s_v;
                ac0 = fmaf(tq, a10, ac0); ac1 = fmaf(tq, a11, ac1); ac2 = fmaf(tq, a12, ac2);
            } else if (grp == 2) {
                const float tq = cA * a0;
                ac0 = fmaf(tq, vx, ac0);  ac1 = fmaf(tq, vy, ac1);  ac2 = fmaf(tq, vz, ac2);
            } else {
                ac0 = fmaf(cA * INV3, vx*a10 + vy*a11 + vz*a12, ac0);
            }
        }
    }

    float* ad = acc + (size_t)n * 256;
    if (grp == 0)      { ad[v] = ac0; }
    else if (grp == 3) { ad[32 + v] = ac0; }
    else if (grp == 1) { ad[64  + 3*v] = ac0; ad[65  + 3*v] = ac1; ad[66  + 3*v] = ac2; }
    else               { ad[160 + 3*v] = ac0; ad[161 + 3*v] = ac1; ad[162 + 3*v] = ac2; }
}

// ---------------- K3: final node linears ----------------
__global__ __launch_bounds__(256) void node_out_kernel(
    const float* __restrict__ acc,
    const float* __restrict__ lin_ws,
    const float* __restrict__ lin_wv,
    float* __restrict__ out)
{
    const int idx = blockIdx.x * 256 + threadIdx.x;
    if (idx >= NN * 32) return;
    const int n = idx >> 5, o = idx & 31;
    const float* a = acc + (size_t)n * 256;

    float os = 0.f, ov0 = 0.f, ov1 = 0.f, ov2 = 0.f;
    #pragma unroll
    for (int u = 0; u < 64; ++u) {
        os = fmaf(a[u], lin_ws[u*32 + o], os);
        const float w = lin_wv[u*32 + o];
        ov0 = fmaf(a[64 + 3*u + 0], w, ov0);
        ov1 = fmaf(a[64 + 3*u + 1], w, ov1);
        ov2 = fmaf(a[64 + 3*u + 2], w, ov2);
    }
    float* on = out + (size_t)n * 128;
    on[o]            = os  * 0.125f;
    on[32 + 3*o + 0] = ov0 * 0.125f;
    on[32 + 3*o + 1] = ov1 * 0.125f;
    on[32 + 3*o + 2] = ov2 * 0.125f;
}

extern "C" void kernel_launch(void* const* d_in, const int* in_sizes, int n_in,
                              void* d_out, int out_size, void* d_ws, size_t ws_size,
                              hipStream_t stream) {
    const int*   esrc    = (const int*)  d_in[0];
    const int*   edst    = (const int*)  d_in[1];
    const float* xattr   = (const float*)d_in[2];
    const float* eattr   = (const float*)d_in[3];
    const float* cutoff  = (const float*)d_in[4];
    const float* node_f  = (const float*)d_in[5];
    const float* k_w1    = (const float*)d_in[6];
    const float* k_w2    = (const float*)d_in[7];
    const float* v_w1    = (const float*)d_in[8];
    const float* v_w2    = (const float*)d_in[9];
    const float* w_ss    = (const float*)d_in[10];
    const float* w_vv    = (const float*)d_in[11];
    const float* lin_ws  = (const float*)d_in[12];
    const float* lin_wv  = (const float*)d_in[13];
    float* out = (float*)d_out;

    // ws: floats [t NN*256 | acc NN*256 | z NN | expw NE]
    //     ushorts [Avb NE*128]
    //     ints [cnt NN | rowptr NN+1 | woff NN | perm NE]   (~126 MB)
    float*  t    = (float*)d_ws;
    float*  acc  = t + (size_t)NN * 256;
    float*  z    = acc + (size_t)NN * 256;
    float*  expw = z + NN;
    ushort* Avb  = (ushort*)(expw + NE);
    int*    cnt    = (int*)(Avb + (size_t)NE * 128);
    int*    rowptr = cnt + NN;
    int*    woff   = rowptr + NN + 1;
    int*    perm   = woff + NN;

    hipMemsetAsync(z, 0, NN * sizeof(float), stream);
    hipMemsetAsync(cnt, 0, NN * sizeof(int), stream);

    node_transform_kernel<<<(NN*32 + 255)/256, 256, 0, stream>>>(node_f, w_ss, w_vv, t);

    hist_kernel<<<(NE + 255)/256, 256, 0, stream>>>(edst, cnt);
    scan_kernel<<<1, 256, 0, stream>>>(cnt, rowptr, woff);
    scatter_kernel<<<(NE + 255)/256, 256, 0, stream>>>(edst, woff, perm);

    edge_gemm_kernel<<<NE/64, 256, 0, stream>>>(
        esrc, edst, xattr, eattr, cutoff, node_f,
        k_w1, k_w2, v_w1, v_w2, t, expw, z, Avb);

    value_kernel<<<NN, 128, 0, stream>>>(
        rowptr, perm, esrc, eattr, node_f, Avb, expw, z, acc);

    node_out_kernel<<<(NN*32 + 255)/256, 256, 0, stream>>>(acc, lin_ws, lin_wv, out);
}

// Round 6
// 318.885 us; speedup vs baseline: 2.3769x; 1.3804x over previous
//
#include <hip/hip_runtime.h>
#include <math.h>

// Equivariant graph attention (Transformer_79302276153378), MI355X.
// Round 6: (a) w2 bf16-split hoisted to a one-time pre-swizzled global image
// (kills per-block conversion VALU + 8-way LDS write conflicts); (b) edge GEMM
// walks CSR order (t[dst] locality, expw/Avb stored CSR-linear); (c) value
// kernel = one wave per node, zero LDS/barriers; (d) multi-block scan.

constexpr int NN = 20000;
constexpr int NE = 320000;
constexpr float INV3      = 0.57735026918962576f;  // 1/sqrt(3)
constexpr float INV_SQRT8 = 0.35355339059327373f;  // 1/sqrt(R_DIM)

typedef __attribute__((ext_vector_type(8))) short bf16x8;
typedef __attribute__((ext_vector_type(4))) float f32x4;

__device__ __forceinline__ float gelu_tanh(float p) {
    float y = 0.7978845608028654f * (p + 0.044715f * p * p * p);
    return p / (1.0f + __expf(-2.0f * y));
}
__device__ __forceinline__ ushort bf16_rn(float f) {
    unsigned u = __float_as_uint(f);
    unsigned r = (u + 0x7FFFu + ((u >> 16) & 1u)) >> 16;
    return (ushort)r;
}
__device__ __forceinline__ float bf16_f(ushort h) {
    return __uint_as_float(((unsigned)h) << 16);
}

// ---------------- K0: per-node dst transform ----------------
__global__ __launch_bounds__(256) void node_transform_kernel(
    const float* __restrict__ node_f,
    const float* __restrict__ w_ss,
    const float* __restrict__ w_vv,
    float* __restrict__ t)            // (NN,32,8)
{
    __shared__ float lws[2048];
    __shared__ float lwv[2048];
    const int tid = threadIdx.x;
    for (int i = tid; i < 2048; i += 256) { lws[i] = w_ss[i]; lwv[i] = w_vv[i]; }
    __syncthreads();

    const int idx = blockIdx.x * 256 + tid;
    if (idx >= NN * 32) return;
    const int n = idx >> 5, v = idx & 31;
    const float* nf = node_f + (size_t)n * 128;

    float t0 = 0.f, t1 = 0.f;
    float tv00 = 0.f, tv01 = 0.f, tv02 = 0.f;
    float tv10 = 0.f, tv11 = 0.f, tv12 = 0.f;
    #pragma unroll
    for (int u = 0; u < 32; ++u) {
        const float s  = nf[u];
        const float vx = nf[32 + 3*u + 0];
        const float vy = nf[32 + 3*u + 1];
        const float vz = nf[32 + 3*u + 2];
        const float a = lws[u*32 + v];
        const float b = lws[1024 + u*32 + v];
        const float c = lwv[u*32 + v];
        const float d = lwv[1024 + u*32 + v];
        t0 = fmaf(s, a, t0);  t1 = fmaf(s, b, t1);
        tv00 = fmaf(vx, c, tv00); tv01 = fmaf(vy, c, tv01); tv02 = fmaf(vz, c, tv02);
        tv10 = fmaf(vx, d, tv10); tv11 = fmaf(vy, d, tv11); tv12 = fmaf(vz, d, tv12);
    }
    float4* o = (float4*)(t + (size_t)idx * 8);
    o[0] = make_float4(t0, t1, tv00 * INV3, tv01 * INV3);
    o[1] = make_float4(tv02 * INV3, tv10 * INV3, tv11 * INV3, tv12 * INV3);
}

// ---------------- w2 -> pre-swizzled bf16 hi/lo image (one-time) -------------
// img[ph][0..8191]=hi, img[ph][8192..16383]=lo, at sw=(n<<6)|(k^((n&7)<<3)).
__global__ __launch_bounds__(256) void w2img_kernel(
    const float* __restrict__ k_w2, const float* __restrict__ v_w2,
    ushort* __restrict__ img)
{
    const int i = blockIdx.x * 256 + threadIdx.x;   // 0..16383
    if (i >= 16384) return;
    const int ph = i >> 13, r = i & 8191;
    const int k = r >> 7, n = r & 127;
    const float f = (ph ? v_w2 : k_w2)[r];
    const ushort hi = bf16_rn(f);
    const ushort lo = bf16_rn(f - bf16_f(hi));
    const int sw = (n << 6) | (k ^ ((n & 7) << 3));
    img[(size_t)ph * 16384 + sw] = hi;
    img[(size_t)ph * 16384 + 8192 + sw] = lo;
}

// ---------------- CSR build ----------------
__global__ __launch_bounds__(256) void hist_kernel(
    const int* __restrict__ edst, int* __restrict__ cnt)
{
    const int e = blockIdx.x * 256 + threadIdx.x;
    if (e < NE) atomicAdd(&cnt[edst[e]], 1);
}

__global__ __launch_bounds__(256) void scanA_kernel(
    const int* __restrict__ cnt, int* __restrict__ rowptr, int* __restrict__ bsum)
{
    __shared__ int buf[256];
    const int i = blockIdx.x * 256 + threadIdx.x;
    const int v = (i < NN) ? cnt[i] : 0;
    buf[threadIdx.x] = v;
    __syncthreads();
    #pragma unroll
    for (int off = 1; off < 256; off <<= 1) {
        const int tc = (threadIdx.x >= off) ? buf[threadIdx.x - off] : 0;
        __syncthreads();
        buf[threadIdx.x] += tc;
        __syncthreads();
    }
    if (i < NN) rowptr[i] = buf[threadIdx.x] - v;       // local exclusive
    if (threadIdx.x == 255) bsum[blockIdx.x] = buf[255];
}

__global__ __launch_bounds__(128) void scanB_kernel(
    const int* __restrict__ bsum, int* __restrict__ boff, int* __restrict__ rowptr)
{
    __shared__ int b[128];
    const int tid = threadIdx.x;
    const int v = (tid < 79) ? bsum[tid] : 0;
    b[tid] = v;
    __syncthreads();
    #pragma unroll
    for (int off = 1; off < 128; off <<= 1) {
        const int tc = (tid >= off) ? b[tid - off] : 0;
        __syncthreads();
        b[tid] += tc;
        __syncthreads();
    }
    boff[tid] = b[tid] - v;                             // exclusive
    if (tid == 0) rowptr[NN] = NE;
}

__global__ __launch_bounds__(256) void scanC_kernel(
    int* __restrict__ rowptr, const int* __restrict__ boff, int* __restrict__ woff)
{
    const int i = blockIdx.x * 256 + threadIdx.x;
    if (i < NN) {
        const int r = rowptr[i] + boff[blockIdx.x];
        rowptr[i] = r;
        woff[i] = r;
    }
}

__global__ __launch_bounds__(256) void scatter_kernel(
    const int* __restrict__ edst, int* __restrict__ woff, int* __restrict__ perm)
{
    const int e = blockIdx.x * 256 + threadIdx.x;
    if (e < NE) {
        const int pos = atomicAdd(&woff[edst[e]], 1);
        perm[pos] = e;
    }
}

// ---------------- edge GEMM over CSR order + fused logit / A_v store ---------
// 64 CSR slots/block, 256 threads (4 waves x 16-edge M-tile). A-frag row=c,
// k=g*8 (+32ks); C: col=lane&15, row=g*4+reg. XOR swizzle ^((row&7)<<3).
__global__ __launch_bounds__(256, 3) void edge_gemm_kernel(
    const int*   __restrict__ perm,
    const int*   __restrict__ esrc,
    const int*   __restrict__ edst,
    const float* __restrict__ xattr,
    const float* __restrict__ eattr,
    const float* __restrict__ cutoff,
    const float* __restrict__ node_f,
    const float* __restrict__ k_w1,
    const float* __restrict__ v_w1,
    const ushort* __restrict__ w2img,  // pre-swizzled hi/lo, 2 phases
    const float* __restrict__ t,       // (NN,256)
    float* __restrict__ expw,          // (NE,) CSR order
    float* __restrict__ z,             // (NN,) atomic
    ushort* __restrict__ Avb)          // (NE,128) bf16, CSR order
{
    __shared__ ushort W2hl[16384];            // [hi 8192 | lo 8192], swizzled
    __shared__ ushort Hh[4096], Hl[4096];     // [e:64][k:64] swizzled
    __shared__ __align__(16) float xs[64][8];
    __shared__ float  seat[64][4];
    __shared__ float  cut[64];
    __shared__ int    sdst[64], ssrc[64], eid[64];

    const int tid  = threadIdx.x;
    const int e0   = blockIdx.x * 64;          // CSR base
    const int lane = tid & 63, wv = tid >> 6;
    const int c    = lane & 15, g = lane >> 4;
    const int j    = lane;                     // hidden index for H compute

    if (tid < 64) {
        const int e = perm[e0 + tid];
        eid[tid] = e; sdst[tid] = edst[e]; ssrc[tid] = esrc[e];
        cut[tid] = cutoff[e];
    }
    __syncthreads();
    {
        int i = tid;
        xs[i >> 3][i & 7] = xattr[(size_t)eid[i >> 3]*8 + (i & 7)];
        i = tid + 256;
        xs[i >> 3][i & 7] = xattr[(size_t)eid[i >> 3]*8 + (i & 7)];
        seat[tid >> 2][tid & 3] = eattr[(size_t)eid[tid >> 2]*4 + (tid & 3)];
    }

    for (int ph = 0; ph < 2; ++ph) {
        const float* w1 = ph ? v_w1 : k_w1;
        __syncthreads();   // staging visible (ph0) / prior frag reads done (ph1)

        // linear 32KB copy of pre-swizzled w2 image -> LDS (conflict-free)
        {
            uint4* d = (uint4*)W2hl;
            const uint4* s = (const uint4*)(w2img + (size_t)ph * 16384);
            #pragma unroll
            for (int i = tid; i < 2048; i += 256) d[i] = s[i];
        }
        // H = gelu(x @ w1 / sqrt(8)), bf16 split, swizzled store
        {
            float w1c[8];
            #pragma unroll
            for (int r = 0; r < 8; ++r) w1c[r] = w1[r*64 + j];
            #pragma unroll
            for (int tt = 0; tt < 16; ++tt) {
                const int e = (tid >> 6) + 4*tt;
                const float4* xp = (const float4*)xs[e];
                const float4 x0 = xp[0], x1 = xp[1];
                float p = x0.x*w1c[0];
                p = fmaf(x0.y, w1c[1], p); p = fmaf(x0.z, w1c[2], p);
                p = fmaf(x0.w, w1c[3], p); p = fmaf(x1.x, w1c[4], p);
                p = fmaf(x1.y, w1c[5], p); p = fmaf(x1.z, w1c[6], p);
                p = fmaf(x1.w, w1c[7], p);
                const float h = gelu_tanh(p * INV_SQRT8);
                const ushort hi = bf16_rn(h);
                const ushort lo = bf16_rn(h - bf16_f(hi));
                const int sw = (e << 6) | (j ^ ((e & 7) << 3));
                Hh[sw] = hi; Hl[sw] = lo;
            }
        }
        __syncthreads();

        // MFMA: wave wv owns edges [eb, eb+16)
        const int eb = wv * 16;
        bf16x8 ah[2], al[2];
        #pragma unroll
        for (int ks = 0; ks < 2; ++ks) {
            const int row = eb + c;
            const int kb  = ks*32 + g*8;
            const int ad  = (row << 6) | (kb ^ ((row & 7) << 3));
            ah[ks] = *(const bf16x8*)&Hh[ad];
            al[ks] = *(const bf16x8*)&Hl[ad];
        }
        f32x4 acc[8];
        #pragma unroll
        for (int nt = 0; nt < 8; ++nt) acc[nt] = (f32x4){0.f, 0.f, 0.f, 0.f};
        #pragma unroll
        for (int nt = 0; nt < 8; ++nt) {
            const int n = nt*16 + c;
            #pragma unroll
            for (int ks = 0; ks < 2; ++ks) {
                const int kb = ks*32 + g*8;
                const int bd = (n << 6) | (kb ^ ((n & 7) << 3));
                const bf16x8 bh = *(const bf16x8*)&W2hl[bd];
                const bf16x8 bl = *(const bf16x8*)&W2hl[8192 + bd];
                acc[nt] = __builtin_amdgcn_mfma_f32_16x16x32_bf16(ah[ks], bh, acc[nt], 0, 0, 0);
                acc[nt] = __builtin_amdgcn_mfma_f32_16x16x32_bf16(al[ks], bh, acc[nt], 0, 0, 0);
                acc[nt] = __builtin_amdgcn_mfma_f32_16x16x32_bf16(ah[ks], bl, acc[nt], 0, 0, 0);
            }
        }

        if (ph == 0) {
            // fused logit: logit = (P_e . t[dst]) * 0.125/64 (t now CSR-local)
            float contrib[4] = {0.f, 0.f, 0.f, 0.f};
            #pragma unroll
            for (int r = 0; r < 4; ++r) {
                const int el  = eb + g*4 + r;
                const int dst = sdst[el], src = ssrc[el];
                const float a0  = seat[el][0], a1x = seat[el][1];
                const float a1y = seat[el][2], a1z = seat[el][3];
                const float* tp = t + (size_t)dst * 256;
                const float* np = node_f + (size_t)src * 128;
                #pragma unroll
                for (int hf = 0; hf < 2; ++hf) {
                    const int v = c + 16*hf;
                    const float A0 = acc[0+hf][r], A1 = acc[2+hf][r];
                    const float A2 = acc[4+hf][r], A3 = acc[6+hf][r];
                    const float4 t4a = *(const float4*)(tp + v*8);
                    const float4 t4b = *(const float4*)(tp + v*8 + 4);
                    const float s_v = np[v];
                    const float vx = np[32+3*v], vy = np[33+3*v], vz = np[34+3*v];
                    const float svd = vx*a1x + vy*a1y + vz*a1z;
                    contrib[r] += t4a.x * (A0 * s_v * a0)
                                + t4a.y * (A3 * svd * INV3)
                                + (A1 * s_v) * (t4a.z*a1x + t4a.w*a1y + t4b.x*a1z)
                                + (A2 * a0)  * (t4b.y*vx + t4b.z*vy + t4b.w*vz);
                }
            }
            #pragma unroll
            for (int r = 0; r < 4; ++r) {
                #pragma unroll
                for (int m = 1; m < 16; m <<= 1)
                    contrib[r] += __shfl_xor(contrib[r], m, 64);
            }
            if (c == 0) {
                #pragma unroll
                for (int r = 0; r < 4; ++r) {
                    const int el = eb + g*4 + r;
                    const float logit = contrib[r] * (0.125f / 64.0f);
                    const float ex = cut[el] * expf(logit);
                    expw[e0 + el] = ex;                 // CSR order
                    unsafeAtomicAdd(&z[sdst[el]], ex);
                }
            }
        } else {
            // store A_v bf16 at CSR index (value kernel reads linearly)
            #pragma unroll
            for (int nt = 0; nt < 8; ++nt) {
                #pragma unroll
                for (int r = 0; r < 4; ++r) {
                    const int el = eb + g*4 + r;
                    Avb[(size_t)(e0 + el)*128 + nt*16 + c] = bf16_rn(acc[nt][r]);
                }
            }
        }
    }
}

// ---------------- values: one wave per node, no LDS / barriers ---------------
__global__ __launch_bounds__(256) void value_kernel(
    const int*   __restrict__ rowptr,
    const int*   __restrict__ perm,
    const int*   __restrict__ esrc,
    const float* __restrict__ eattr,
    const float* __restrict__ node_f,
    const ushort* __restrict__ Avb,    // (NE,128) CSR order
    const float* __restrict__ expw,    // (NE,) CSR order
    const float* __restrict__ z,
    float* __restrict__ acc)           // (NN,256)
{
    const int wv = threadIdx.x >> 6, lane = threadIdx.x & 63;
    const int n = blockIdx.x * 4 + wv;
    const int v = lane & 31;

    float zv = z[n];
    if (zv == 0.f) zv = 1.f;
    const float inv_z = 1.0f / zv;
    const int k0 = rowptr[n], k1 = rowptr[n + 1];

    float a_0 = 0.f, a_1 = 0.f, a_2 = 0.f, a_3 = 0.f, a_4 = 0.f, a_5 = 0.f;

    for (int k = k0; k < k1; ++k) {
        const float cf = sqrtf(expw[k] * inv_z) * 0.125f;   // sqrt(alpha)/8
        const int e = perm[k];
        const float4 ea = *(const float4*)(eattr + (size_t)e * 4);
        const int src = esrc[e];
        const float* np = node_f + (size_t)src * 128;
        const float s_v = np[v];
        const float vx = np[32 + 3*v], vy = np[33 + 3*v], vz = np[34 + 3*v];
        const ushort* av = Avb + (size_t)k * 128;
        if (lane < 32) {
            const float A0 = bf16_f(av[v]), A3 = bf16_f(av[96 + v]);
            a_0 = fmaf(cf * A0, s_v * ea.x, a_0);
            a_1 = fmaf(cf * A3 * INV3, vx*ea.y + vy*ea.z + vz*ea.w, a_1);
        } else {
            const float A1 = bf16_f(av[32 + v]), A2 = bf16_f(av[64 + v]);
            const float t1 = cf * A1 * s_v, t2 = cf * A2 * ea.x;
            a_0 = fmaf(t1, ea.y, a_0); a_1 = fmaf(t1, ea.z, a_1); a_2 = fmaf(t1, ea.w, a_2);
            a_3 = fmaf(t2, vx, a_3);   a_4 = fmaf(t2, vy, a_4);   a_5 = fmaf(t2, vz, a_5);
        }
    }

    float* ad = acc + (size_t)n * 256;
    if (lane < 32) {
        ad[v] = a_0; ad[32 + v] = a_1;
    } else {
        ad[64  + 3*v] = a_0; ad[65  + 3*v] = a_1; ad[66  + 3*v] = a_2;
        ad[160 + 3*v] = a_3; ad[161 + 3*v] = a_4; ad[162 + 3*v] = a_5;
    }
}

// ---------------- K3: final node linears ----------------
__global__ __launch_bounds__(256) void node_out_kernel(
    const float* __restrict__ acc,
    const float* __restrict__ lin_ws,
    const float* __restrict__ lin_wv,
    float* __restrict__ out)
{
    const int idx = blockIdx.x * 256 + threadIdx.x;
    if (idx >= NN * 32) return;
    const int n = idx >> 5, o = idx & 31;
    const float* a = acc + (size_t)n * 256;

    float os = 0.f, ov0 = 0.f, ov1 = 0.f, ov2 = 0.f;
    #pragma unroll
    for (int u = 0; u < 64; ++u) {
        os = fmaf(a[u], lin_ws[u*32 + o], os);
        const float w = lin_wv[u*32 + o];
        ov0 = fmaf(a[64 + 3*u + 0], w, ov0);
        ov1 = fmaf(a[64 + 3*u + 1], w, ov1);
        ov2 = fmaf(a[64 + 3*u + 2], w, ov2);
    }
    float* on = out + (size_t)n * 128;
    on[o]            = os  * 0.125f;
    on[32 + 3*o + 0] = ov0 * 0.125f;
    on[32 + 3*o + 1] = ov1 * 0.125f;
    on[32 + 3*o + 2] = ov2 * 0.125f;
}

extern "C" void kernel_launch(void* const* d_in, const int* in_sizes, int n_in,
                              void* d_out, int out_size, void* d_ws, size_t ws_size,
                              hipStream_t stream) {
    const int*   esrc    = (const int*)  d_in[0];
    const int*   edst    = (const int*)  d_in[1];
    const float* xattr   = (const float*)d_in[2];
    const float* eattr   = (const float*)d_in[3];
    const float* cutoff  = (const float*)d_in[4];
    const float* node_f  = (const float*)d_in[5];
    const float* k_w1    = (const float*)d_in[6];
    const float* k_w2    = (const float*)d_in[7];
    const float* v_w1    = (const float*)d_in[8];
    const float* v_w2    = (const float*)d_in[9];
    const float* w_ss    = (const float*)d_in[10];
    const float* w_vv    = (const float*)d_in[11];
    const float* lin_ws  = (const float*)d_in[12];
    const float* lin_wv  = (const float*)d_in[13];
    float* out = (float*)d_out;

    // ws: floats [t NN*256 | acc NN*256 | z NN | expw NE]
    //     ushorts [Avb NE*128 | w2img 32768]
    //     ints [cnt NN | rowptr NN+1 | woff NN | perm NE | bsum 128 | boff 128]
    float*  t     = (float*)d_ws;
    float*  acc   = t + (size_t)NN * 256;
    float*  z     = acc + (size_t)NN * 256;
    float*  expw  = z + NN;
    ushort* Avb   = (ushort*)(expw + NE);
    ushort* w2img = Avb + (size_t)NE * 128;
    int*    cnt    = (int*)(w2img + 32768);
    int*    rowptr = cnt + NN;
    int*    woff   = rowptr + NN + 1;
    int*    perm   = woff + NN;
    int*    bsum   = perm + NE;
    int*    boff   = bsum + 128;

    hipMemsetAsync(z, 0, NN * sizeof(float), stream);
    hipMemsetAsync(cnt, 0, NN * sizeof(int), stream);

    node_transform_kernel<<<(NN*32 + 255)/256, 256, 0, stream>>>(node_f, w_ss, w_vv, t);
    w2img_kernel<<<64, 256, 0, stream>>>(k_w2, v_w2, w2img);

    hist_kernel<<<(NE + 255)/256, 256, 0, stream>>>(edst, cnt);
    scanA_kernel<<<(NN + 255)/256, 256, 0, stream>>>(cnt, rowptr, bsum);
    scanB_kernel<<<1, 128, 0, stream>>>(bsum, boff, rowptr);
    scanC_kernel<<<(NN + 255)/256, 256, 0, stream>>>(rowptr, boff, woff);
    scatter_kernel<<<(NE + 255)/256, 256, 0, stream>>>(edst, woff, perm);

    edge_gemm_kernel<<<NE/64, 256, 0, stream>>>(
        perm, esrc, edst, xattr, eattr, cutoff, node_f,
        k_w1, v_w1, w2img, t, expw, z, Avb);

    value_kernel<<<NN/4, 256, 0, stream>>>(
        rowptr, perm, esrc, eattr, node_f, Avb, expw, z, acc);

    node_out_kernel<<<(NN*32 + 255)/256, 256, 0, stream>>>(acc, lin_ws, lin_wv, out);
}